// Round 3
// baseline (551.794 us; speedup 1.0000x reference)
//
#include <hip/hip_runtime.h>
#include <math.h>

#define BQ 2
#define LQ 4096
#define DM 768
#define DI 1536
#define DS 16
#define E80 80   // DTR + 2*DS
#define NC 32
#define CH 128   // LQ / NC

typedef _Float16 half8 __attribute__((ext_vector_type(8)));
typedef _Float16 half4v __attribute__((ext_vector_type(4)));
typedef float f32x4 __attribute__((ext_vector_type(4)));

__device__ __forceinline__ ushort f2h_bits(float x) {
    return __builtin_bit_cast(ushort, (_Float16)x);
}

// Direct global->LDS DMA, 16B per lane. LDS dst must be wave-uniform base;
// HW writes base + lane*16 (== our Af[frag][lane] layout exactly).
#define GLDS16(gsrc, ldst)                                                  \
    __builtin_amdgcn_global_load_lds(                                       \
        (const __attribute__((address_space(1))) void*)(gsrc),              \
        (__attribute__((address_space(3))) void*)(ldst), 16, 0, 0)

// ---------------------------------------------------------------------------
// f32 -> fp16 pack (n divisible by 1024; grid = n/1024)
// ---------------------------------------------------------------------------
__global__ __launch_bounds__(256)
void pack_fp16(const float* __restrict__ src, _Float16* __restrict__ dst)
{
    long i = ((long)blockIdx.x * 256 + threadIdx.x) * 4;
    float4 v = *(const float4*)(src + i);
    half4v o = {(_Float16)v.x, (_Float16)v.y, (_Float16)v.z, (_Float16)v.w};
    *(half4v*)(dst + i) = o;
}

// ---------------------------------------------------------------------------
// dt_proj weights -> fp16 [br][d][64], zero-padded k=48..63. grid 12x256.
// ---------------------------------------------------------------------------
__global__ __launch_bounds__(256)
void pack_dtw(const float* __restrict__ dwa, const float* __restrict__ dwb,
              _Float16* __restrict__ dtw)
{
    int idx = blockIdx.x * 256 + threadIdx.x;   // 0 .. 2*DI-1
    int br = idx / DI, d = idx % DI;
    const float* W = (br ? dwb : dwa) + (long)d * 48;
    _Float16* o = dtw + (long)idx * 64;
#pragma unroll
    for (int k = 0; k < 48; k++) o[k] = (_Float16)W[k];
#pragma unroll
    for (int k = 48; k < 64; k++) o[k] = (_Float16)0.f;
}

// ---------------------------------------------------------------------------
// MFMA NT GEMM (fp16 in, CT out): C[m,n] = sum_k A[m,k]*B[n,k].
// 128x128 tile, BK=64. Fragment-ordered LDS (uint4): [frag][lane] x16B.
// R3: occupancy attack. R2 counters: MfmaUtil 17 / VALU 23 / HBM 14 /
// Occupancy 27% -> latency-bound with ~140 unified regs/wave (76 VGPR +
// 64 acc AGPR) capping waves/SIMD at ~2. Changes:
//  (1) stream a-frags one at a time (live uint4s 32->20),
//  (2) __launch_bounds__(256,4): pin allocator at <=128 regs/wave,
//  (3) bijective XCD-chunked blockIdx swizzle (nwg%8==0 at both call
//      sites) so panel-sharing blocks co-reside on one XCD's L2.
// NOTE: all __shared__ arrays in this file are 32-bit+ types ON PURPOSE —
// 16-bit-typed shared arrays correlate with container-killing faults
// (R4/R5/R7 died, R2/R3/R6/R8/R9 passed).
// ---------------------------------------------------------------------------
template <typename CT>
__global__ __launch_bounds__(256, 4)
void gemm_mfma(const _Float16* __restrict__ Ah, const _Float16* __restrict__ Bh,
               CT* __restrict__ C, int K, int ldA, int ldB, int ldC,
               long strideA, long strideB, long strideC)
{
    __shared__ uint4 Af[16][64];
    __shared__ uint4 Bf[16][64];

    // XCD-chunked bijective swizzle over the linear block id (m204 pattern,
    // simplified for nwg % 8 == 0): new = (lin%8)*(nwg/8) + lin/8.
    const int nwg = gridDim.x * gridDim.y * gridDim.z;
    int lin = (blockIdx.z * gridDim.y + blockIdx.y) * gridDim.x + blockIdx.x;
    lin = (lin & 7) * (nwg >> 3) + (lin >> 3);
    const int bx = lin % gridDim.x;
    const int by = (lin / gridDim.x) % gridDim.y;
    const int bz = lin / (gridDim.x * gridDim.y);

    const _Float16* Ab = Ah + (long)bz * strideA;
    const _Float16* Bb = Bh + (long)bz * strideB;
    CT* Cb = C + (long)bz * strideC;
    const int m0 = by * 128, n0 = bx * 128;
    const int tid = threadIdx.x, w = tid >> 6, lane = tid & 63;
    const int mh = w & 1, nh = w >> 1;

    const _Float16* asrc[4];
    const _Float16* bsrc[4];
#pragma unroll
    for (int i = 0; i < 4; i++) {
        int f = w * 4 + i;
        int ks = f >> 3, t = f & 7;
        asrc[i] = Ab + (long)(m0 + t * 16 + (lane & 15)) * ldA + ks * 32 + (lane >> 4) * 8;
        bsrc[i] = Bb + (long)(n0 + t * 16 + (lane & 15)) * ldB + ks * 32 + (lane >> 4) * 8;
    }

    f32x4 acc[4][4];
#pragma unroll
    for (int i = 0; i < 4; i++)
#pragma unroll
        for (int j = 0; j < 4; j++) acc[i][j] = {0.f, 0.f, 0.f, 0.f};

    for (int k0 = 0; k0 < K; k0 += 64) {
#pragma unroll
        for (int i = 0; i < 4; i++) {
            GLDS16(asrc[i], &Af[w * 4 + i][0]);
            GLDS16(bsrc[i], &Bf[w * 4 + i][0]);
            asrc[i] += 64; bsrc[i] += 64;
        }
        __syncthreads();
#pragma unroll
        for (int ks = 0; ks < 2; ks++) {
            uint4 bu[4];
#pragma unroll
            for (int j = 0; j < 4; j++)
                bu[j] = Bf[ks * 8 + nh * 4 + j][lane];
#pragma unroll
            for (int i = 0; i < 4; i++) {
                uint4 au = Af[ks * 8 + mh * 4 + i][lane];
                half8 av = __builtin_bit_cast(half8, au);
#pragma unroll
                for (int j = 0; j < 4; j++) {
                    half8 bv = __builtin_bit_cast(half8, bu[j]);
                    acc[i][j] = __builtin_amdgcn_mfma_f32_16x16x32_f16(
                        av, bv, acc[i][j], 0, 0, 0);
                }
            }
        }
        __syncthreads();
    }
    const int r0 = (lane >> 4) * 4, cn = lane & 15;
#pragma unroll
    for (int i = 0; i < 4; i++) {
        int mrow = m0 + (mh * 4 + i) * 16 + r0;
#pragma unroll
        for (int j = 0; j < 4; j++) {
            int col = n0 + (nh * 4 + j) * 16 + cn;
#pragma unroll
            for (int r = 0; r < 4; r++)
                Cb[(long)(mrow + r) * ldC + col] = (CT)acc[i][j][r];
        }
    }
}

// ---------------------------------------------------------------------------
// Depthwise conv(k=4)+SiLU with transpose: xz x-half [b][d][l] fp16 ->
// u_t fp16 [z][l][d]. br=1 consumes reversed sequence.
// ---------------------------------------------------------------------------
__global__ __launch_bounds__(256)
void conv_silu_t(const _Float16* __restrict__ xz,
                 const float* __restrict__ cwa, const float* __restrict__ cba,
                 const float* __restrict__ cwb, const float* __restrict__ cbb,
                 _Float16* __restrict__ ut)
{
    __shared__ float lraw[64][67];
    __shared__ float cu[64][72];
    __shared__ float lcw[64][5];
    const int l0 = blockIdx.x * 64, d0 = blockIdx.y * 64;
    const int z = blockIdx.z;
    const int br = z >> 1, b = z & 1;
    const _Float16* xb = xz + ((long)b * 2 * DI + d0) * LQ;
    const float* CW = br ? cwb : cwa;
    const float* CB = br ? cbb : cba;
    const int tid = threadIdx.x;

    {
        int dd = tid >> 2, k = tid & 3;
        lcw[dd][k] = CW[(d0 + dd) * 4 + k];
        if (tid < 64) lcw[tid][4] = CB[d0 + tid];
    }
    for (int i = tid; i < 64 * 67; i += 256) {
        int dd = i / 67, cc = i % 67;
        int src = l0 - 3 + cc;
        float v = 0.f;
        if (src >= 0)
            v = (float)xb[(long)dd * LQ + (br ? (LQ - 1 - src) : src)];
        lraw[dd][cc] = v;
    }
    __syncthreads();
#pragma unroll
    for (int q = 0; q < 16; q++) {
        int o = tid + q * 256;
        int dd = o & 63, ll = o >> 6;
        float a = lcw[dd][4];
        a = fmaf(lraw[dd][ll + 0], lcw[dd][0], a);
        a = fmaf(lraw[dd][ll + 1], lcw[dd][1], a);
        a = fmaf(lraw[dd][ll + 2], lcw[dd][2], a);
        a = fmaf(lraw[dd][ll + 3], lcw[dd][3], a);
        cu[ll][dd] = a * (1.f / (1.f + __expf(-a)));
    }
    __syncthreads();
    const int dg = (tid & 7) * 8;
#pragma unroll
    for (int p = 0; p < 2; p++) {
        int ll = (tid >> 3) + p * 32;
        float4 v0 = *(const float4*)&cu[ll][dg];
        float4 v1 = *(const float4*)&cu[ll][dg + 4];
        uint4 o;
        o.x = f2h_bits(v0.x) | ((unsigned)f2h_bits(v0.y) << 16);
        o.y = f2h_bits(v0.z) | ((unsigned)f2h_bits(v0.w) << 16);
        o.z = f2h_bits(v1.x) | ((unsigned)f2h_bits(v1.y) << 16);
        o.w = f2h_bits(v1.z) | ((unsigned)f2h_bits(v1.w) << 16);
        *(uint4*)(ut + ((long)z * LQ + l0 + ll) * DI + d0 + dg) = o;
    }
}

// ---------------------------------------------------------------------------
// x_proj MFMA GEMM: dbl[z][l][e] = sum_d u_t[z][l][d] * xpw[br][e][d].
// ---------------------------------------------------------------------------
__global__ __launch_bounds__(256)
void xproj_mfma(const _Float16* __restrict__ ut, const _Float16* __restrict__ xpw,
                float* __restrict__ dbl)
{
    __shared__ uint4 Af[8][64];
    __shared__ uint4 Bf[10][64];
    const int m0 = blockIdx.x * 64;
    const int z = blockIdx.y;
    const _Float16* A = ut + (long)z * LQ * DI;
    const _Float16* W = xpw + (long)(z >> 1) * E80 * DI;
    float* out = dbl + (long)z * LQ * E80;
    const int tid = threadIdx.x, w = tid >> 6, lane = tid & 63;

    f32x4 acc[5];
#pragma unroll
    for (int j = 0; j < 5; j++) acc[j] = {0.f, 0.f, 0.f, 0.f};

    for (int k0 = 0; k0 < DI; k0 += 64) {
#pragma unroll
        for (int i = 0; i < 2; i++) {
            int f = w + i * 4;
            int row = m0 + (f & 3) * 16 + (lane & 15);
            int koff = k0 + (f >> 2) * 32 + (lane >> 4) * 8;
            Af[f][lane] = *(const uint4*)(A + (long)row * DI + koff);
        }
        for (int i = tid; i < 640; i += 256) {
            int f = i >> 6, ln = i & 63;
            int e = (f >> 1) * 16 + (ln & 15);
            int koff = k0 + (f & 1) * 32 + (ln >> 4) * 8;
            Bf[f][ln] = *(const uint4*)(W + (long)e * DI + koff);
        }
        __syncthreads();
#pragma unroll
        for (int ks = 0; ks < 2; ks++) {
            half8 av = __builtin_bit_cast(half8, Af[ks * 4 + w][lane]);
#pragma unroll
            for (int j = 0; j < 5; j++) {
                half8 bv = __builtin_bit_cast(half8, Bf[j * 2 + ks][lane]);
                acc[j] = __builtin_amdgcn_mfma_f32_16x16x32_f16(av, bv, acc[j], 0, 0, 0);
            }
        }
        __syncthreads();
    }
    const int r0 = (lane >> 4) * 4, cn = lane & 15;
    const int row = m0 + w * 16 + r0;
#pragma unroll
    for (int j = 0; j < 5; j++)
#pragma unroll
        for (int r = 0; r < 4; r++)
            out[(long)(row + r) * E80 + j * 16 + cn] = acc[j][r];
}

// ---------------------------------------------------------------------------
// delta MFMA GEMM + softplus.
// Softplus uses the fast native pipeline: __logf(1+__expf(a)) ==
// v_exp_f32 + v_log_f32 + 2 muls. log1pf (OCML libm) was ~270 VALU
// instr/elem and made this kernel 95% VALUBusy / 90 us (R0 counters).
// ---------------------------------------------------------------------------
__global__ __launch_bounds__(256)
void delta_mfma(const float* __restrict__ dbl, const _Float16* __restrict__ dtw,
                const float* __restrict__ dba, const float* __restrict__ dbb,
                _Float16* __restrict__ dlt)
{
    __shared__ uint4 Af[8][64];
    __shared__ uint4 Bf[16][64];
    const int m0 = blockIdx.x * 64;
    const int n0 = blockIdx.y * 128;
    const int z  = blockIdx.z;
    const float* bias = (z >> 1) ? dbb : dba;
    const float* Ab = dbl + (long)z * LQ * E80;
    const _Float16* Wb = dtw + (long)(z >> 1) * DI * 64;
    _Float16* ob = dlt + (long)z * LQ * DI;
    const int tid = threadIdx.x, w = tid >> 6, lane = tid & 63;

#pragma unroll
    for (int i = 0; i < 2; i++) {
        int s = tid + i * 256;
        int f = s >> 6, ln = s & 63;
        int mt = f >> 1, ks = f & 1;
        int row = m0 + mt * 16 + (ln & 15);
        int koff = ks * 32 + (ln >> 4) * 8;
        uint4 o = {0u, 0u, 0u, 0u};
        if (koff < 48) {
            const float* p = Ab + (long)row * E80 + koff;
            float4 v0 = *(const float4*)p;
            float4 v1 = *(const float4*)(p + 4);
            o.x = f2h_bits(v0.x) | ((unsigned)f2h_bits(v0.y) << 16);
            o.y = f2h_bits(v0.z) | ((unsigned)f2h_bits(v0.w) << 16);
            o.z = f2h_bits(v1.x) | ((unsigned)f2h_bits(v1.y) << 16);
            o.w = f2h_bits(v1.z) | ((unsigned)f2h_bits(v1.w) << 16);
        }
        Af[f][ln] = o;
    }
#pragma unroll
    for (int i = 0; i < 4; i++) {
        int s = tid + i * 256;
        int f = s >> 6, ln = s & 63;
        int nt = f >> 1, ks = f & 1;
        int d = n0 + nt * 16 + (ln & 15);
        int koff = ks * 32 + (ln >> 4) * 8;
        Bf[f][ln] = *(const uint4*)(Wb + (long)d * 64 + koff);
    }
    __syncthreads();

    f32x4 acc[8];
#pragma unroll
    for (int j = 0; j < 8; j++) acc[j] = {0.f, 0.f, 0.f, 0.f};
#pragma unroll
    for (int ks = 0; ks < 2; ks++) {
        half8 av = __builtin_bit_cast(half8, Af[w * 2 + ks][lane]);
#pragma unroll
        for (int j = 0; j < 8; j++) {
            half8 bv = __builtin_bit_cast(half8, Bf[j * 2 + ks][lane]);
            acc[j] = __builtin_amdgcn_mfma_f32_16x16x32_f16(av, bv, acc[j], 0, 0, 0);
        }
    }
    const int r0 = (lane >> 4) * 4, cn = lane & 15;
    const int row = m0 + w * 16 + r0;
#pragma unroll
    for (int j = 0; j < 8; j++) {
        int d = n0 + j * 16 + cn;
        float bi = bias[d];
#pragma unroll
        for (int r = 0; r < 4; r++) {
            float a = acc[j][r] + bi;
            float sp = (a > 20.f) ? a : __logf(1.f + __expf(a));
            ob[(long)(row + r) * DI + d] = (_Float16)sp;
        }
    }
}

// ---------------------------------------------------------------------------
// Transpose z-half of xz [b][DI..2DI][l] fp16 -> z_t fp16 [b][l][d].
// ---------------------------------------------------------------------------
__global__ __launch_bounds__(256)
void transpose_z(const _Float16* __restrict__ xz, _Float16* __restrict__ zt)
{
    __shared__ float t[64][65];
    const int l0 = blockIdx.x * 64, d0 = blockIdx.y * 64, b = blockIdx.z;
    const _Float16* src = xz + ((long)b * 2 * DI + DI + d0) * LQ + l0;
    const int tid = threadIdx.x;
#pragma unroll
    for (int p = 0; p < 2; p++) {
        int g = tid + p * 256;
        int dd = g >> 3, c8 = (g & 7) * 8;
        half8 v = *(const half8*)&src[(long)dd * LQ + c8];
#pragma unroll
        for (int j = 0; j < 8; j++) t[c8 + j][dd] = (float)v[j];
    }
    __syncthreads();
    const int l = tid >> 2, seg = (tid & 3) * 16;
    ushort tmp[16];
#pragma unroll
    for (int j = 0; j < 16; j++) tmp[j] = f2h_bits(t[l][seg + j]);
    uint4 p0, p1;
    p0.x = tmp[0] | (tmp[1] << 16);  p0.y = tmp[2] | (tmp[3] << 16);
    p0.z = tmp[4] | (tmp[5] << 16);  p0.w = tmp[6] | (tmp[7] << 16);
    p1.x = tmp[8] | (tmp[9] << 16);  p1.y = tmp[10] | (tmp[11] << 16);
    p1.z = tmp[12] | (tmp[13] << 16); p1.w = tmp[14] | (tmp[15] << 16);
    ushort* dst = (ushort*)(zt + ((long)b * LQ + l0 + l) * DI + d0 + seg);
    *(uint4*)dst = p0;
    *(uint4*)(dst + 8) = p1;
}

// ---------------------------------------------------------------------------
// Scan pass 1: per-chunk summaries (lane = channel, 16 states in VGPRs).
// Fast path: A[d][n] == -(n+1) (the problem's A_log = log(1..16)) lets
// exp(dl*An[n]) = r^(n+1), r = exp(-dl): 1 exp + 15 muls instead of 16 exps.
// Verified per-thread with tolerance; general fallback otherwise.
// ---------------------------------------------------------------------------
__global__ __launch_bounds__(256)
void scan_p1(const _Float16* __restrict__ ut, const _Float16* __restrict__ dlt,
             const float* __restrict__ dbl,
             const float* __restrict__ Ala, const float* __restrict__ Alb,
             float* __restrict__ Sdl, float* __restrict__ Hloc)
{
    const int d = blockIdx.x * 256 + threadIdx.x;
    const int c = blockIdx.y;
    const int z = blockIdx.z;
    const int br = z >> 1;
    const float* Al = br ? Alb : Ala;
    float An[16];
#pragma unroll
    for (int i = 0; i < 4; i++) {
        float4 v = *(const float4*)&Al[(long)d * 16 + i * 4];
        An[i * 4] = -__expf(v.x); An[i * 4 + 1] = -__expf(v.y);
        An[i * 4 + 2] = -__expf(v.z); An[i * 4 + 3] = -__expf(v.w);
    }
    bool fast = true;
#pragma unroll
    for (int n = 0; n < 16; n++)
        fast = fast && (__builtin_fabsf(An[n] + (float)(n + 1)) < 1e-3f);

    const long lbase = (long)z * LQ + (long)c * CH;
    const _Float16* ub = ut + lbase * DI + d;
    const _Float16* db = dlt + lbase * DI + d;
    const float* bc = dbl + lbase * E80 + 48;

    float h[16];
#pragma unroll
    for (int n = 0; n < 16; n++) h[n] = 0.f;
    float sdl = 0.f;

    for (int t0 = 0; t0 < CH; t0 += 8) {
        _Float16 uu[8], dd[8];
#pragma unroll
        for (int j = 0; j < 8; j++) {
            uu[j] = ub[(long)(t0 + j) * DI];
            dd[j] = db[(long)(t0 + j) * DI];
        }
#pragma unroll
        for (int j = 0; j < 8; j++) {
            float dl = (float)dd[j];
            float u  = (float)uu[j];
            sdl += dl;
            float du = dl * u;
            const float* Bp = bc + (long)(t0 + j) * E80;
            float Bv[16];
#pragma unroll
            for (int i = 0; i < 4; i++) {
                float4 v = *(const float4*)&Bp[i * 4];
                Bv[i * 4] = v.x; Bv[i * 4 + 1] = v.y;
                Bv[i * 4 + 2] = v.z; Bv[i * 4 + 3] = v.w;
            }
            if (fast) {
                float r = __expf(-dl);
                float p = r;
                h[0] = fmaf(p, h[0], du * Bv[0]);
#pragma unroll
                for (int n = 1; n < 16; n++) {
                    p *= r;
                    h[n] = fmaf(p, h[n], du * Bv[n]);
                }
            } else {
#pragma unroll
                for (int n = 0; n < 16; n++)
                    h[n] = fmaf(__expf(dl * An[n]), h[n], du * Bv[n]);
            }
        }
    }
    Sdl[((long)z * NC + c) * DI + d] = sdl;
    float* Hp = Hloc + (((long)z * NC + c) * DI + d) * 16;
#pragma unroll
    for (int i = 0; i < 4; i++)
        *(float4*)&Hp[i * 4] = make_float4(h[i * 4], h[i * 4 + 1], h[i * 4 + 2], h[i * 4 + 3]);
}

// ---------------------------------------------------------------------------
// Scan pass 2: inter-chunk scan.
// ---------------------------------------------------------------------------
__global__ __launch_bounds__(256)
void scan_p2(const float* __restrict__ Sdl, const float* __restrict__ Hloc,
             const float* __restrict__ Ala, const float* __restrict__ Alb,
             float* __restrict__ h0)
{
    const int idx = blockIdx.x * 256 + threadIdx.x;
    const int z = blockIdx.y;
    const int d = idx >> 4, n = idx & 15;
    const float* Al = (z >> 1) ? Alb : Ala;
    const float An = -__expf(Al[(long)d * 16 + n]);
    float h = 0.f;
    for (int c = 0; c < NC; c++) {
        h0[((long)z * NC + c) * DI * 16 + idx] = h;
        float sdl = Sdl[((long)z * NC + c) * DI + d];
        float Hl = Hloc[((long)z * NC + c) * DI * 16 + idx];
        h = fmaf(__expf(An * sdl), h, Hl);
    }
}

// ---------------------------------------------------------------------------
// Scan pass 3: re-run chunks from h0, emit y (+D) fp16 [l][d], B pre-flipped.
// Same fast path as scan_p1.
// ---------------------------------------------------------------------------
__global__ __launch_bounds__(256)
void scan_p3(const _Float16* __restrict__ ut, const _Float16* __restrict__ dlt,
             const float* __restrict__ dbl, const float* __restrict__ h0,
             const float* __restrict__ Ala, const float* __restrict__ Alb,
             const float* __restrict__ Da, const float* __restrict__ Db,
             _Float16* __restrict__ ya, _Float16* __restrict__ yb)
{
    const int d = blockIdx.x * 256 + threadIdx.x;
    const int c = blockIdx.y;
    const int z = blockIdx.z;
    const int br = z >> 1, b = z & 1;
    const float* Al = br ? Alb : Ala;
    float An[16];
#pragma unroll
    for (int i = 0; i < 4; i++) {
        float4 v = *(const float4*)&Al[(long)d * 16 + i * 4];
        An[i * 4] = -__expf(v.x); An[i * 4 + 1] = -__expf(v.y);
        An[i * 4 + 2] = -__expf(v.z); An[i * 4 + 3] = -__expf(v.w);
    }
    bool fast = true;
#pragma unroll
    for (int n = 0; n < 16; n++)
        fast = fast && (__builtin_fabsf(An[n] + (float)(n + 1)) < 1e-3f);

    const float Dd = (br ? Db : Da)[d];
    const long lbase = (long)z * LQ + (long)c * CH;
    const _Float16* ub = ut + lbase * DI + d;
    const _Float16* db = dlt + lbase * DI + d;
    const float* bc = dbl + lbase * E80 + 48;
    const float* Hp = h0 + (((long)z * NC + c) * DI + d) * 16;
    float h[16];
#pragma unroll
    for (int i = 0; i < 4; i++) {
        float4 v = *(const float4*)&Hp[i * 4];
        h[i * 4] = v.x; h[i * 4 + 1] = v.y; h[i * 4 + 2] = v.z; h[i * 4 + 3] = v.w;
    }
    _Float16* yo = br ? yb : ya;

    for (int t0 = 0; t0 < CH; t0 += 8) {
        _Float16 uu[8], dd[8];
#pragma unroll
        for (int j = 0; j < 8; j++) {
            uu[j] = ub[(long)(t0 + j) * DI];
            dd[j] = db[(long)(t0 + j) * DI];
        }
#pragma unroll
        for (int j = 0; j < 8; j++) {
            float dl = (float)dd[j];
            float u  = (float)uu[j];
            float du = dl * u;
            const float* Bp = bc + (long)(t0 + j) * E80;
            float Bv[16], Cv[16];
#pragma unroll
            for (int i = 0; i < 4; i++) {
                float4 v = *(const float4*)&Bp[i * 4];
                Bv[i * 4] = v.x; Bv[i * 4 + 1] = v.y;
                Bv[i * 4 + 2] = v.z; Bv[i * 4 + 3] = v.w;
                float4 w2 = *(const float4*)&Bp[16 + i * 4];
                Cv[i * 4] = w2.x; Cv[i * 4 + 1] = w2.y;
                Cv[i * 4 + 2] = w2.z; Cv[i * 4 + 3] = w2.w;
            }
            float y = u * Dd;
            if (fast) {
                float r = __expf(-dl);
                float p = r;
                h[0] = fmaf(p, h[0], du * Bv[0]);
                y = fmaf(h[0], Cv[0], y);
#pragma unroll
                for (int n = 1; n < 16; n++) {
                    p *= r;
                    h[n] = fmaf(p, h[n], du * Bv[n]);
                    y = fmaf(h[n], Cv[n], y);
                }
            } else {
#pragma unroll
                for (int n = 0; n < 16; n++) {
                    h[n] = fmaf(__expf(dl * An[n]), h[n], du * Bv[n]);
                    y = fmaf(h[n], Cv[n], y);
                }
            }
            int t = c * CH + t0 + j;
            long lorig = br ? (LQ - 1 - t) : t;
            yo[((long)b * LQ + lorig) * DI + d] = (_Float16)y;
        }
    }
}

// ---------------------------------------------------------------------------
// yf = (ya + yb) * silu(z)  -> fp16 [b][l][d]. 8 elements/thread.
// ---------------------------------------------------------------------------
__global__ __launch_bounds__(256)
void fuse_y(const _Float16* __restrict__ ya, const _Float16* __restrict__ yb,
            const _Float16* __restrict__ zt, _Float16* __restrict__ yf)
{
    long i = ((long)blockIdx.x * 256 + threadIdx.x) * 8;
    half8 a = *(const half8*)(ya + i);
    half8 b = *(const half8*)(yb + i);
    half8 zz = *(const half8*)(zt + i);
    half8 o;
#pragma unroll
    for (int j = 0; j < 8; j++) {
        float y = (float)a[j] + (float)b[j];
        float zv = (float)zz[j];
        o[j] = (_Float16)(y * (zv / (1.f + __expf(-zv))));
    }
    *(half8*)(yf + i) = o;
}

// ---------------------------------------------------------------------------
extern "C" void kernel_launch(void* const* d_in, const int* in_sizes, int n_in,
                              void* d_out, int out_size, void* d_ws, size_t ws_size,
                              hipStream_t stream)
{
    const float* hs  = (const float*)d_in[0];
    const float* Wi  = (const float*)d_in[1];
    const float* Wo  = (const float*)d_in[2];
    const float* cwa = (const float*)d_in[3];
    const float* cba = (const float*)d_in[4];
    const float* cwb = (const float*)d_in[5];
    const float* cbb = (const float*)d_in[6];
    const float* xpa = (const float*)d_in[7];
    const float* xpb = (const float*)d_in[8];
    const float* dwa = (const float*)d_in[9];
    const float* dwb = (const float*)d_in[10];
    const float* dba = (const float*)d_in[11];
    const float* dbb = (const float*)d_in[12];
    const float* Ala = (const float*)d_in[13];
    const float* Alb = (const float*)d_in[14];
    const float* Da  = (const float*)d_in[15];
    const float* Db  = (const float*)d_in[16];
    float* out = (float*)d_out;

    float* ws = (float*)d_ws;
    _Float16* xz   = (_Float16*)ws;                     // fp16 now: [0 .. 12582912) floats-worth
    _Float16* dl_t = (_Float16*)ws;                     // same extent as xz (xz dead first)
    _Float16* ya   = (_Float16*)(ws + 12582912);
    _Float16* yb   = (_Float16*)(ws + 18874368);
    float*    dbl  = ws + 25165824;                     // [.. 26476544)
    _Float16* u_t  = (_Float16*)(ws + 26476544);        // [.. 39059456)
    _Float16* yf   = (_Float16*)(ws + 26476544);        // aliases u_t (dead after p3)
    _Float16* z_t  = (_Float16*)(ws + 39059456);        // [.. 45350912)
    float*    Sdl  = ws + 45350912;                     // [.. 45547520)
    float*    Hloc = ws + 45547520;                     // [.. 48693248)
    float*    h0   = ws + 48693248;                     // [.. 51838976)
    _Float16* hsb  = (_Float16*)(ws + 45350912);        // dead pre-scan
    _Float16* Wib  = (_Float16*)(ws + 48496640);        // dead pre-scan
    _Float16* xpw  = (_Float16*)(ws + 49676288);        // dead pre-scan
    _Float16* dtw  = (_Float16*)(ws + 49799168);        // dead pre-scan
    _Float16* Wob  = (_Float16*)(ws + 45350912);        // packed AFTER scan_p3
    // peak footprint: 51,838,976 floats = 207.36 MB (== R3/R6/R8/R9 layout)

    // 0) fp16 packs
    pack_fp16<<<6144, 256, 0, stream>>>(hs, hsb);
    pack_fp16<<<2304, 256, 0, stream>>>(Wi, Wib);
    pack_fp16<<<120, 256, 0, stream>>>(xpa, xpw);
    pack_fp16<<<120, 256, 0, stream>>>(xpb, xpw + 122880);
    pack_dtw<<<12, 256, 0, stream>>>(dwa, dwb, dtw);
    // 1) in_proj (MFMA, fp16 out)
    gemm_mfma<_Float16><<<dim3(32, 24, 2), 256, 0, stream>>>(
        Wib, hsb, xz, DM, DM, DM, LQ,
        0L, (long)LQ * DM, (long)2 * DI * LQ);
    // 2) conv+silu with transpose -> u_t fp16 [z][l][d]
    conv_silu_t<<<dim3(64, 24, 4), 256, 0, stream>>>(xz, cwa, cba, cwb, cbb, u_t);
    // 3) x_proj (MFMA)
    xproj_mfma<<<dim3(64, 4), 256, 0, stream>>>(u_t, xpw, dbl);
    // 4) z transpose (last reader of xz)
    transpose_z<<<dim3(64, 24, 2), 256, 0, stream>>>(xz, z_t);
    // 5) delta via MFMA + fused softplus (overwrites xz region)
    delta_mfma<<<dim3(64, 12, 4), 256, 0, stream>>>(dbl, dtw, dba, dbb, dl_t);
    // 6) chunked scan
    scan_p1<<<dim3(6, NC, 4), 256, 0, stream>>>(u_t, dl_t, dbl, Ala, Alb, Sdl, Hloc);
    scan_p2<<<dim3(96, 4), 256, 0, stream>>>(Sdl, Hloc, Ala, Alb, h0);
    scan_p3<<<dim3(6, NC, 4), 256, 0, stream>>>(u_t, dl_t, dbl, h0, Ala, Alb, Da, Db, ya, yb);
    // 7) pack Wo (Sdl dead now); fuse (ya+yb)*silu(z)
    pack_fp16<<<1152, 256, 0, stream>>>(Wo, Wob);
    fuse_y<<<6144, 256, 0, stream>>>(ya, yb, z_t, yf);
    // 8) out_proj (MFMA, f32 out)
    gemm_mfma<float><<<dim3(6, 32, 2), 256, 0, stream>>>(
        yf, Wob, out, DI, DI, DI, DM,
        (long)LQ * DI, 0L, (long)LQ * DM);
}

// Round 4
// 544.295 us; speedup vs baseline: 1.0138x; 1.0138x over previous
//
#include <hip/hip_runtime.h>
#include <math.h>

#define BQ 2
#define LQ 4096
#define DM 768
#define DI 1536
#define DS 16
#define E80 80   // DTR + 2*DS
#define NC 32
#define CH 128   // LQ / NC

typedef _Float16 half8 __attribute__((ext_vector_type(8)));
typedef _Float16 half4v __attribute__((ext_vector_type(4)));
typedef float f32x4 __attribute__((ext_vector_type(4)));

__device__ __forceinline__ ushort f2h_bits(float x) {
    return __builtin_bit_cast(ushort, (_Float16)x);
}

// Direct global->LDS DMA, 16B per lane. LDS dst must be wave-uniform base;
// HW writes base + lane*16 (== our Af[frag][lane] layout exactly).
#define GLDS16(gsrc, ldst)                                                  \
    __builtin_amdgcn_global_load_lds(                                       \
        (const __attribute__((address_space(1))) void*)(gsrc),              \
        (__attribute__((address_space(3))) void*)(ldst), 16, 0, 0)

// ---------------------------------------------------------------------------
// f32 -> fp16 pack (n divisible by 1024; grid = n/1024)
// ---------------------------------------------------------------------------
__global__ __launch_bounds__(256)
void pack_fp16(const float* __restrict__ src, _Float16* __restrict__ dst)
{
    long i = ((long)blockIdx.x * 256 + threadIdx.x) * 4;
    float4 v = *(const float4*)(src + i);
    half4v o = {(_Float16)v.x, (_Float16)v.y, (_Float16)v.z, (_Float16)v.w};
    *(half4v*)(dst + i) = o;
}

// ---------------------------------------------------------------------------
// dt_proj weights -> fp16 [br][d][64], zero-padded k=48..63. grid 12x256.
// ---------------------------------------------------------------------------
__global__ __launch_bounds__(256)
void pack_dtw(const float* __restrict__ dwa, const float* __restrict__ dwb,
              _Float16* __restrict__ dtw)
{
    int idx = blockIdx.x * 256 + threadIdx.x;   // 0 .. 2*DI-1
    int br = idx / DI, d = idx % DI;
    const float* W = (br ? dwb : dwa) + (long)d * 48;
    _Float16* o = dtw + (long)idx * 64;
#pragma unroll
    for (int k = 0; k < 48; k++) o[k] = (_Float16)W[k];
#pragma unroll
    for (int k = 48; k < 64; k++) o[k] = (_Float16)0.f;
}

// ---------------------------------------------------------------------------
// MFMA NT GEMM (fp16 in, CT out): C[m,n] = sum_k A[m,k]*B[n,k].
// 128x128 tile, BK=64. Fragment-ordered LDS (uint4): [frag][lane] x16B.
// R4: 2-phase double-buffer (T3 minimum recipe). R2/R3 post-mortems:
// counters swung wildly (VGPR 76->60, VALU 23->11, Occ 27->34, FETCH
// 44->110MB) while dur sat at ~85us and MfmaUtil at 17.6% -> the binding
// constraint is the serial K-step (stage -> drain vmcnt(0) -> compute),
// every step paying full load latency. Fix: issue tile t+1's STAGE before
// computing tile t from the other buffer; ONE barrier per iter; the
// implicit vmcnt(0) before s_barrier lands AFTER compute, so load latency
// hides under ds_read+MFMA. XCD swizzle of R3 reverted (measured: 2.5x
// FETCH increase, no dur change).
// NOTE: all __shared__ arrays in this file are 32-bit+ types ON PURPOSE —
// 16-bit-typed shared arrays correlate with container-killing faults
// (R4/R5/R7 died, R2/R3/R6/R8/R9 passed).
// ---------------------------------------------------------------------------
template <typename CT>
__global__ __launch_bounds__(256, 4)
void gemm_mfma(const _Float16* __restrict__ Ah, const _Float16* __restrict__ Bh,
               CT* __restrict__ C, int K, int ldA, int ldB, int ldC,
               long strideA, long strideB, long strideC)
{
    __shared__ uint4 Af[2][16][64];
    __shared__ uint4 Bf[2][16][64];
    const int bz = blockIdx.z;
    const _Float16* Ab = Ah + (long)bz * strideA;
    const _Float16* Bb = Bh + (long)bz * strideB;
    CT* Cb = C + (long)bz * strideC;
    const int m0 = blockIdx.y * 128, n0 = blockIdx.x * 128;
    const int tid = threadIdx.x, w = tid >> 6, lane = tid & 63;
    const int mh = w & 1, nh = w >> 1;

    const _Float16* asrc[4];
    const _Float16* bsrc[4];
#pragma unroll
    for (int i = 0; i < 4; i++) {
        int f = w * 4 + i;
        int ks = f >> 3, t = f & 7;
        asrc[i] = Ab + (long)(m0 + t * 16 + (lane & 15)) * ldA + ks * 32 + (lane >> 4) * 8;
        bsrc[i] = Bb + (long)(n0 + t * 16 + (lane & 15)) * ldB + ks * 32 + (lane >> 4) * 8;
    }

    f32x4 acc[4][4];
#pragma unroll
    for (int i = 0; i < 4; i++)
#pragma unroll
        for (int j = 0; j < 4; j++) acc[i][j] = {0.f, 0.f, 0.f, 0.f};

    const int nt = K >> 6;   // K-steps of 64

    // prologue: stage tile 0 into buf 0
#pragma unroll
    for (int i = 0; i < 4; i++) {
        GLDS16(asrc[i], &Af[0][w * 4 + i][0]);
        GLDS16(bsrc[i], &Bf[0][w * 4 + i][0]);
        asrc[i] += 64; bsrc[i] += 64;
    }
    __syncthreads();

    int cur = 0;
    for (int t = 0; t < nt; ++t) {
        // issue next tile's loads into the other buffer (in flight during
        // this tile's ds_read+MFMA)
        if (t + 1 < nt) {
#pragma unroll
            for (int i = 0; i < 4; i++) {
                GLDS16(asrc[i], &Af[cur ^ 1][w * 4 + i][0]);
                GLDS16(bsrc[i], &Bf[cur ^ 1][w * 4 + i][0]);
                asrc[i] += 64; bsrc[i] += 64;
            }
        }
        // compute tile t from buf[cur]
#pragma unroll
        for (int ks = 0; ks < 2; ks++) {
            uint4 bu[4];
#pragma unroll
            for (int j = 0; j < 4; j++)
                bu[j] = Bf[cur][ks * 8 + nh * 4 + j][lane];
#pragma unroll
            for (int i = 0; i < 4; i++) {
                uint4 au = Af[cur][ks * 8 + mh * 4 + i][lane];
                half8 av = __builtin_bit_cast(half8, au);
#pragma unroll
                for (int j = 0; j < 4; j++) {
                    half8 bv = __builtin_bit_cast(half8, bu[j]);
                    acc[i][j] = __builtin_amdgcn_mfma_f32_16x16x32_f16(
                        av, bv, acc[i][j], 0, 0, 0);
                }
            }
        }
        __syncthreads();   // drains prefetch (compiler emits vmcnt(0)) +
                           // guards buffer reuse; one barrier per K-step
        cur ^= 1;
    }

    const int r0 = (lane >> 4) * 4, cn = lane & 15;
#pragma unroll
    for (int i = 0; i < 4; i++) {
        int mrow = m0 + (mh * 4 + i) * 16 + r0;
#pragma unroll
        for (int j = 0; j < 4; j++) {
            int col = n0 + (nh * 4 + j) * 16 + cn;
#pragma unroll
            for (int r = 0; r < 4; r++)
                Cb[(long)(mrow + r) * ldC + col] = (CT)acc[i][j][r];
        }
    }
}

// ---------------------------------------------------------------------------
// Depthwise conv(k=4)+SiLU with transpose: xz x-half [b][d][l] fp16 ->
// u_t fp16 [z][l][d]. br=1 consumes reversed sequence.
// ---------------------------------------------------------------------------
__global__ __launch_bounds__(256)
void conv_silu_t(const _Float16* __restrict__ xz,
                 const float* __restrict__ cwa, const float* __restrict__ cba,
                 const float* __restrict__ cwb, const float* __restrict__ cbb,
                 _Float16* __restrict__ ut)
{
    __shared__ float lraw[64][67];
    __shared__ float cu[64][72];
    __shared__ float lcw[64][5];
    const int l0 = blockIdx.x * 64, d0 = blockIdx.y * 64;
    const int z = blockIdx.z;
    const int br = z >> 1, b = z & 1;
    const _Float16* xb = xz + ((long)b * 2 * DI + d0) * LQ;
    const float* CW = br ? cwb : cwa;
    const float* CB = br ? cbb : cba;
    const int tid = threadIdx.x;

    {
        int dd = tid >> 2, k = tid & 3;
        lcw[dd][k] = CW[(d0 + dd) * 4 + k];
        if (tid < 64) lcw[tid][4] = CB[d0 + tid];
    }
    for (int i = tid; i < 64 * 67; i += 256) {
        int dd = i / 67, cc = i % 67;
        int src = l0 - 3 + cc;
        float v = 0.f;
        if (src >= 0)
            v = (float)xb[(long)dd * LQ + (br ? (LQ - 1 - src) : src)];
        lraw[dd][cc] = v;
    }
    __syncthreads();
#pragma unroll
    for (int q = 0; q < 16; q++) {
        int o = tid + q * 256;
        int dd = o & 63, ll = o >> 6;
        float a = lcw[dd][4];
        a = fmaf(lraw[dd][ll + 0], lcw[dd][0], a);
        a = fmaf(lraw[dd][ll + 1], lcw[dd][1], a);
        a = fmaf(lraw[dd][ll + 2], lcw[dd][2], a);
        a = fmaf(lraw[dd][ll + 3], lcw[dd][3], a);
        cu[ll][dd] = a * (1.f / (1.f + __expf(-a)));
    }
    __syncthreads();
    const int dg = (tid & 7) * 8;
#pragma unroll
    for (int p = 0; p < 2; p++) {
        int ll = (tid >> 3) + p * 32;
        float4 v0 = *(const float4*)&cu[ll][dg];
        float4 v1 = *(const float4*)&cu[ll][dg + 4];
        uint4 o;
        o.x = f2h_bits(v0.x) | ((unsigned)f2h_bits(v0.y) << 16);
        o.y = f2h_bits(v0.z) | ((unsigned)f2h_bits(v0.w) << 16);
        o.z = f2h_bits(v1.x) | ((unsigned)f2h_bits(v1.y) << 16);
        o.w = f2h_bits(v1.z) | ((unsigned)f2h_bits(v1.w) << 16);
        *(uint4*)(ut + ((long)z * LQ + l0 + ll) * DI + d0 + dg) = o;
    }
}

// ---------------------------------------------------------------------------
// x_proj MFMA GEMM: dbl[z][l][e] = sum_d u_t[z][l][d] * xpw[br][e][d].
// ---------------------------------------------------------------------------
__global__ __launch_bounds__(256)
void xproj_mfma(const _Float16* __restrict__ ut, const _Float16* __restrict__ xpw,
                float* __restrict__ dbl)
{
    __shared__ uint4 Af[8][64];
    __shared__ uint4 Bf[10][64];
    const int m0 = blockIdx.x * 64;
    const int z = blockIdx.y;
    const _Float16* A = ut + (long)z * LQ * DI;
    const _Float16* W = xpw + (long)(z >> 1) * E80 * DI;
    float* out = dbl + (long)z * LQ * E80;
    const int tid = threadIdx.x, w = tid >> 6, lane = tid & 63;

    f32x4 acc[5];
#pragma unroll
    for (int j = 0; j < 5; j++) acc[j] = {0.f, 0.f, 0.f, 0.f};

    for (int k0 = 0; k0 < DI; k0 += 64) {
#pragma unroll
        for (int i = 0; i < 2; i++) {
            int f = w + i * 4;
            int row = m0 + (f & 3) * 16 + (lane & 15);
            int koff = k0 + (f >> 2) * 32 + (lane >> 4) * 8;
            Af[f][lane] = *(const uint4*)(A + (long)row * DI + koff);
        }
        for (int i = tid; i < 640; i += 256) {
            int f = i >> 6, ln = i & 63;
            int e = (f >> 1) * 16 + (ln & 15);
            int koff = k0 + (f & 1) * 32 + (ln >> 4) * 8;
            Bf[f][ln] = *(const uint4*)(W + (long)e * DI + koff);
        }
        __syncthreads();
#pragma unroll
        for (int ks = 0; ks < 2; ks++) {
            half8 av = __builtin_bit_cast(half8, Af[ks * 4 + w][lane]);
#pragma unroll
            for (int j = 0; j < 5; j++) {
                half8 bv = __builtin_bit_cast(half8, Bf[j * 2 + ks][lane]);
                acc[j] = __builtin_amdgcn_mfma_f32_16x16x32_f16(av, bv, acc[j], 0, 0, 0);
            }
        }
        __syncthreads();
    }
    const int r0 = (lane >> 4) * 4, cn = lane & 15;
    const int row = m0 + w * 16 + r0;
#pragma unroll
    for (int j = 0; j < 5; j++)
#pragma unroll
        for (int r = 0; r < 4; r++)
            out[(long)(row + r) * E80 + j * 16 + cn] = acc[j][r];
}

// ---------------------------------------------------------------------------
// delta MFMA GEMM + softplus.
// Softplus uses the fast native pipeline: __logf(1+__expf(a)) ==
// v_exp_f32 + v_log_f32 + 2 muls. log1pf (OCML libm) was ~270 VALU
// instr/elem and made this kernel 95% VALUBusy / 90 us (R0 counters).
// ---------------------------------------------------------------------------
__global__ __launch_bounds__(256)
void delta_mfma(const float* __restrict__ dbl, const _Float16* __restrict__ dtw,
                const float* __restrict__ dba, const float* __restrict__ dbb,
                _Float16* __restrict__ dlt)
{
    __shared__ uint4 Af[8][64];
    __shared__ uint4 Bf[16][64];
    const int m0 = blockIdx.x * 64;
    const int n0 = blockIdx.y * 128;
    const int z  = blockIdx.z;
    const float* bias = (z >> 1) ? dbb : dba;
    const float* Ab = dbl + (long)z * LQ * E80;
    const _Float16* Wb = dtw + (long)(z >> 1) * DI * 64;
    _Float16* ob = dlt + (long)z * LQ * DI;
    const int tid = threadIdx.x, w = tid >> 6, lane = tid & 63;

#pragma unroll
    for (int i = 0; i < 2; i++) {
        int s = tid + i * 256;
        int f = s >> 6, ln = s & 63;
        int mt = f >> 1, ks = f & 1;
        int row = m0 + mt * 16 + (ln & 15);
        int koff = ks * 32 + (ln >> 4) * 8;
        uint4 o = {0u, 0u, 0u, 0u};
        if (koff < 48) {
            const float* p = Ab + (long)row * E80 + koff;
            float4 v0 = *(const float4*)p;
            float4 v1 = *(const float4*)(p + 4);
            o.x = f2h_bits(v0.x) | ((unsigned)f2h_bits(v0.y) << 16);
            o.y = f2h_bits(v0.z) | ((unsigned)f2h_bits(v0.w) << 16);
            o.z = f2h_bits(v1.x) | ((unsigned)f2h_bits(v1.y) << 16);
            o.w = f2h_bits(v1.z) | ((unsigned)f2h_bits(v1.w) << 16);
        }
        Af[f][ln] = o;
    }
#pragma unroll
    for (int i = 0; i < 4; i++) {
        int s = tid + i * 256;
        int f = s >> 6, ln = s & 63;
        int nt = f >> 1, ks = f & 1;
        int d = n0 + nt * 16 + (ln & 15);
        int koff = ks * 32 + (ln >> 4) * 8;
        Bf[f][ln] = *(const uint4*)(Wb + (long)d * 64 + koff);
    }
    __syncthreads();

    f32x4 acc[8];
#pragma unroll
    for (int j = 0; j < 8; j++) acc[j] = {0.f, 0.f, 0.f, 0.f};
#pragma unroll
    for (int ks = 0; ks < 2; ks++) {
        half8 av = __builtin_bit_cast(half8, Af[w * 2 + ks][lane]);
#pragma unroll
        for (int j = 0; j < 8; j++) {
            half8 bv = __builtin_bit_cast(half8, Bf[j * 2 + ks][lane]);
            acc[j] = __builtin_amdgcn_mfma_f32_16x16x32_f16(av, bv, acc[j], 0, 0, 0);
        }
    }
    const int r0 = (lane >> 4) * 4, cn = lane & 15;
    const int row = m0 + w * 16 + r0;
#pragma unroll
    for (int j = 0; j < 8; j++) {
        int d = n0 + j * 16 + cn;
        float bi = bias[d];
#pragma unroll
        for (int r = 0; r < 4; r++) {
            float a = acc[j][r] + bi;
            float sp = (a > 20.f) ? a : __logf(1.f + __expf(a));
            ob[(long)(row + r) * DI + d] = (_Float16)sp;
        }
    }
}

// ---------------------------------------------------------------------------
// Transpose z-half of xz [b][DI..2DI][l] fp16 -> z_t fp16 [b][l][d].
// ---------------------------------------------------------------------------
__global__ __launch_bounds__(256)
void transpose_z(const _Float16* __restrict__ xz, _Float16* __restrict__ zt)
{
    __shared__ float t[64][65];
    const int l0 = blockIdx.x * 64, d0 = blockIdx.y * 64, b = blockIdx.z;
    const _Float16* src = xz + ((long)b * 2 * DI + DI + d0) * LQ + l0;
    const int tid = threadIdx.x;
#pragma unroll
    for (int p = 0; p < 2; p++) {
        int g = tid + p * 256;
        int dd = g >> 3, c8 = (g & 7) * 8;
        half8 v = *(const half8*)&src[(long)dd * LQ + c8];
#pragma unroll
        for (int j = 0; j < 8; j++) t[c8 + j][dd] = (float)v[j];
    }
    __syncthreads();
    const int l = tid >> 2, seg = (tid & 3) * 16;
    ushort tmp[16];
#pragma unroll
    for (int j = 0; j < 16; j++) tmp[j] = f2h_bits(t[l][seg + j]);
    uint4 p0, p1;
    p0.x = tmp[0] | (tmp[1] << 16);  p0.y = tmp[2] | (tmp[3] << 16);
    p0.z = tmp[4] | (tmp[5] << 16);  p0.w = tmp[6] | (tmp[7] << 16);
    p1.x = tmp[8] | (tmp[9] << 16);  p1.y = tmp[10] | (tmp[11] << 16);
    p1.z = tmp[12] | (tmp[13] << 16); p1.w = tmp[14] | (tmp[15] << 16);
    ushort* dst = (ushort*)(zt + ((long)b * LQ + l0 + l) * DI + d0 + seg);
    *(uint4*)dst = p0;
    *(uint4*)(dst + 8) = p1;
}

// ---------------------------------------------------------------------------
// Scan pass 1: per-chunk summaries (lane = channel, 16 states in VGPRs).
// Fast path: A[d][n] == -(n+1) (the problem's A_log = log(1..16)) lets
// exp(dl*An[n]) = r^(n+1), r = exp(-dl): 1 exp + 15 muls instead of 16 exps.
// Verified per-thread with tolerance; general fallback otherwise.
// ---------------------------------------------------------------------------
__global__ __launch_bounds__(256)
void scan_p1(const _Float16* __restrict__ ut, const _Float16* __restrict__ dlt,
             const float* __restrict__ dbl,
             const float* __restrict__ Ala, const float* __restrict__ Alb,
             float* __restrict__ Sdl, float* __restrict__ Hloc)
{
    const int d = blockIdx.x * 256 + threadIdx.x;
    const int c = blockIdx.y;
    const int z = blockIdx.z;
    const int br = z >> 1;
    const float* Al = br ? Alb : Ala;
    float An[16];
#pragma unroll
    for (int i = 0; i < 4; i++) {
        float4 v = *(const float4*)&Al[(long)d * 16 + i * 4];
        An[i * 4] = -__expf(v.x); An[i * 4 + 1] = -__expf(v.y);
        An[i * 4 + 2] = -__expf(v.z); An[i * 4 + 3] = -__expf(v.w);
    }
    bool fast = true;
#pragma unroll
    for (int n = 0; n < 16; n++)
        fast = fast && (__builtin_fabsf(An[n] + (float)(n + 1)) < 1e-3f);

    const long lbase = (long)z * LQ + (long)c * CH;
    const _Float16* ub = ut + lbase * DI + d;
    const _Float16* db = dlt + lbase * DI + d;
    const float* bc = dbl + lbase * E80 + 48;

    float h[16];
#pragma unroll
    for (int n = 0; n < 16; n++) h[n] = 0.f;
    float sdl = 0.f;

    for (int t0 = 0; t0 < CH; t0 += 8) {
        _Float16 uu[8], dd[8];
#pragma unroll
        for (int j = 0; j < 8; j++) {
            uu[j] = ub[(long)(t0 + j) * DI];
            dd[j] = db[(long)(t0 + j) * DI];
        }
#pragma unroll
        for (int j = 0; j < 8; j++) {
            float dl = (float)dd[j];
            float u  = (float)uu[j];
            sdl += dl;
            float du = dl * u;
            const float* Bp = bc + (long)(t0 + j) * E80;
            float Bv[16];
#pragma unroll
            for (int i = 0; i < 4; i++) {
                float4 v = *(const float4*)&Bp[i * 4];
                Bv[i * 4] = v.x; Bv[i * 4 + 1] = v.y;
                Bv[i * 4 + 2] = v.z; Bv[i * 4 + 3] = v.w;
            }
            if (fast) {
                float r = __expf(-dl);
                float p = r;
                h[0] = fmaf(p, h[0], du * Bv[0]);
#pragma unroll
                for (int n = 1; n < 16; n++) {
                    p *= r;
                    h[n] = fmaf(p, h[n], du * Bv[n]);
                }
            } else {
#pragma unroll
                for (int n = 0; n < 16; n++)
                    h[n] = fmaf(__expf(dl * An[n]), h[n], du * Bv[n]);
            }
        }
    }
    Sdl[((long)z * NC + c) * DI + d] = sdl;
    float* Hp = Hloc + (((long)z * NC + c) * DI + d) * 16;
#pragma unroll
    for (int i = 0; i < 4; i++)
        *(float4*)&Hp[i * 4] = make_float4(h[i * 4], h[i * 4 + 1], h[i * 4 + 2], h[i * 4 + 3]);
}

// ---------------------------------------------------------------------------
// Scan pass 2: inter-chunk scan.
// ---------------------------------------------------------------------------
__global__ __launch_bounds__(256)
void scan_p2(const float* __restrict__ Sdl, const float* __restrict__ Hloc,
             const float* __restrict__ Ala, const float* __restrict__ Alb,
             float* __restrict__ h0)
{
    const int idx = blockIdx.x * 256 + threadIdx.x;
    const int z = blockIdx.y;
    const int d = idx >> 4, n = idx & 15;
    const float* Al = (z >> 1) ? Alb : Ala;
    const float An = -__expf(Al[(long)d * 16 + n]);
    float h = 0.f;
    for (int c = 0; c < NC; c++) {
        h0[((long)z * NC + c) * DI * 16 + idx] = h;
        float sdl = Sdl[((long)z * NC + c) * DI + d];
        float Hl = Hloc[((long)z * NC + c) * DI * 16 + idx];
        h = fmaf(__expf(An * sdl), h, Hl);
    }
}

// ---------------------------------------------------------------------------
// Scan pass 3: re-run chunks from h0, emit y (+D) fp16 [l][d], B pre-flipped.
// Same fast path as scan_p1.
// ---------------------------------------------------------------------------
__global__ __launch_bounds__(256)
void scan_p3(const _Float16* __restrict__ ut, const _Float16* __restrict__ dlt,
             const float* __restrict__ dbl, const float* __restrict__ h0,
             const float* __restrict__ Ala, const float* __restrict__ Alb,
             const float* __restrict__ Da, const float* __restrict__ Db,
             _Float16* __restrict__ ya, _Float16* __restrict__ yb)
{
    const int d = blockIdx.x * 256 + threadIdx.x;
    const int c = blockIdx.y;
    const int z = blockIdx.z;
    const int br = z >> 1, b = z & 1;
    const float* Al = br ? Alb : Ala;
    float An[16];
#pragma unroll
    for (int i = 0; i < 4; i++) {
        float4 v = *(const float4*)&Al[(long)d * 16 + i * 4];
        An[i * 4] = -__expf(v.x); An[i * 4 + 1] = -__expf(v.y);
        An[i * 4 + 2] = -__expf(v.z); An[i * 4 + 3] = -__expf(v.w);
    }
    bool fast = true;
#pragma unroll
    for (int n = 0; n < 16; n++)
        fast = fast && (__builtin_fabsf(An[n] + (float)(n + 1)) < 1e-3f);

    const float Dd = (br ? Db : Da)[d];
    const long lbase = (long)z * LQ + (long)c * CH;
    const _Float16* ub = ut + lbase * DI + d;
    const _Float16* db = dlt + lbase * DI + d;
    const float* bc = dbl + lbase * E80 + 48;
    const float* Hp = h0 + (((long)z * NC + c) * DI + d) * 16;
    float h[16];
#pragma unroll
    for (int i = 0; i < 4; i++) {
        float4 v = *(const float4*)&Hp[i * 4];
        h[i * 4] = v.x; h[i * 4 + 1] = v.y; h[i * 4 + 2] = v.z; h[i * 4 + 3] = v.w;
    }
    _Float16* yo = br ? yb : ya;

    for (int t0 = 0; t0 < CH; t0 += 8) {
        _Float16 uu[8], dd[8];
#pragma unroll
        for (int j = 0; j < 8; j++) {
            uu[j] = ub[(long)(t0 + j) * DI];
            dd[j] = db[(long)(t0 + j) * DI];
        }
#pragma unroll
        for (int j = 0; j < 8; j++) {
            float dl = (float)dd[j];
            float u  = (float)uu[j];
            float du = dl * u;
            const float* Bp = bc + (long)(t0 + j) * E80;
            float Bv[16], Cv[16];
#pragma unroll
            for (int i = 0; i < 4; i++) {
                float4 v = *(const float4*)&Bp[i * 4];
                Bv[i * 4] = v.x; Bv[i * 4 + 1] = v.y;
                Bv[i * 4 + 2] = v.z; Bv[i * 4 + 3] = v.w;
                float4 w2 = *(const float4*)&Bp[16 + i * 4];
                Cv[i * 4] = w2.x; Cv[i * 4 + 1] = w2.y;
                Cv[i * 4 + 2] = w2.z; Cv[i * 4 + 3] = w2.w;
            }
            float y = u * Dd;
            if (fast) {
                float r = __expf(-dl);
                float p = r;
                h[0] = fmaf(p, h[0], du * Bv[0]);
                y = fmaf(h[0], Cv[0], y);
#pragma unroll
                for (int n = 1; n < 16; n++) {
                    p *= r;
                    h[n] = fmaf(p, h[n], du * Bv[n]);
                    y = fmaf(h[n], Cv[n], y);
                }
            } else {
#pragma unroll
                for (int n = 0; n < 16; n++) {
                    h[n] = fmaf(__expf(dl * An[n]), h[n], du * Bv[n]);
                    y = fmaf(h[n], Cv[n], y);
                }
            }
            int t = c * CH + t0 + j;
            long lorig = br ? (LQ - 1 - t) : t;
            yo[((long)b * LQ + lorig) * DI + d] = (_Float16)y;
        }
    }
}

// ---------------------------------------------------------------------------
// yf = (ya + yb) * silu(z)  -> fp16 [b][l][d]. 8 elements/thread.
// ---------------------------------------------------------------------------
__global__ __launch_bounds__(256)
void fuse_y(const _Float16* __restrict__ ya, const _Float16* __restrict__ yb,
            const _Float16* __restrict__ zt, _Float16* __restrict__ yf)
{
    long i = ((long)blockIdx.x * 256 + threadIdx.x) * 8;
    half8 a = *(const half8*)(ya + i);
    half8 b = *(const half8*)(yb + i);
    half8 zz = *(const half8*)(zt + i);
    half8 o;
#pragma unroll
    for (int j = 0; j < 8; j++) {
        float y = (float)a[j] + (float)b[j];
        float zv = (float)zz[j];
        o[j] = (_Float16)(y * (zv / (1.f + __expf(-zv))));
    }
    *(half8*)(yf + i) = o;
}

// ---------------------------------------------------------------------------
extern "C" void kernel_launch(void* const* d_in, const int* in_sizes, int n_in,
                              void* d_out, int out_size, void* d_ws, size_t ws_size,
                              hipStream_t stream)
{
    const float* hs  = (const float*)d_in[0];
    const float* Wi  = (const float*)d_in[1];
    const float* Wo  = (const float*)d_in[2];
    const float* cwa = (const float*)d_in[3];
    const float* cba = (const float*)d_in[4];
    const float* cwb = (const float*)d_in[5];
    const float* cbb = (const float*)d_in[6];
    const float* xpa = (const float*)d_in[7];
    const float* xpb = (const float*)d_in[8];
    const float* dwa = (const float*)d_in[9];
    const float* dwb = (const float*)d_in[10];
    const float* dba = (const float*)d_in[11];
    const float* dbb = (const float*)d_in[12];
    const float* Ala = (const float*)d_in[13];
    const float* Alb = (const float*)d_in[14];
    const float* Da  = (const float*)d_in[15];
    const float* Db  = (const float*)d_in[16];
    float* out = (float*)d_out;

    float* ws = (float*)d_ws;
    _Float16* xz   = (_Float16*)ws;                     // fp16 now: [0 .. 12582912) floats-worth
    _Float16* dl_t = (_Float16*)ws;                     // same extent as xz (xz dead first)
    _Float16* ya   = (_Float16*)(ws + 12582912);
    _Float16* yb   = (_Float16*)(ws + 18874368);
    float*    dbl  = ws + 25165824;                     // [.. 26476544)
    _Float16* u_t  = (_Float16*)(ws + 26476544);        // [.. 39059456)
    _Float16* yf   = (_Float16*)(ws + 26476544);        // aliases u_t (dead after p3)
    _Float16* z_t  = (_Float16*)(ws + 39059456);        // [.. 45350912)
    float*    Sdl  = ws + 45350912;                     // [.. 45547520)
    float*    Hloc = ws + 45547520;                     // [.. 48693248)
    float*    h0   = ws + 48693248;                     // [.. 51838976)
    _Float16* hsb  = (_Float16*)(ws + 45350912);        // dead pre-scan
    _Float16* Wib  = (_Float16*)(ws + 48496640);        // dead pre-scan
    _Float16* xpw  = (_Float16*)(ws + 49676288);        // dead pre-scan
    _Float16* dtw  = (_Float16*)(ws + 49799168);        // dead pre-scan
    _Float16* Wob  = (_Float16*)(ws + 45350912);        // packed AFTER scan_p3
    // peak footprint: 51,838,976 floats = 207.36 MB (== R3/R6/R8/R9 layout)

    // 0) fp16 packs
    pack_fp16<<<6144, 256, 0, stream>>>(hs, hsb);
    pack_fp16<<<2304, 256, 0, stream>>>(Wi, Wib);
    pack_fp16<<<120, 256, 0, stream>>>(xpa, xpw);
    pack_fp16<<<120, 256, 0, stream>>>(xpb, xpw + 122880);
    pack_dtw<<<12, 256, 0, stream>>>(dwa, dwb, dtw);
    // 1) in_proj (MFMA, fp16 out)
    gemm_mfma<_Float16><<<dim3(32, 24, 2), 256, 0, stream>>>(
        Wib, hsb, xz, DM, DM, DM, LQ,
        0L, (long)LQ * DM, (long)2 * DI * LQ);
    // 2) conv+silu with transpose -> u_t fp16 [z][l][d]
    conv_silu_t<<<dim3(64, 24, 4), 256, 0, stream>>>(xz, cwa, cba, cwb, cbb, u_t);
    // 3) x_proj (MFMA)
    xproj_mfma<<<dim3(64, 4), 256, 0, stream>>>(u_t, xpw, dbl);
    // 4) z transpose (last reader of xz)
    transpose_z<<<dim3(64, 24, 2), 256, 0, stream>>>(xz, z_t);
    // 5) delta via MFMA + fused softplus (overwrites xz region)
    delta_mfma<<<dim3(64, 12, 4), 256, 0, stream>>>(dbl, dtw, dba, dbb, dl_t);
    // 6) chunked scan
    scan_p1<<<dim3(6, NC, 4), 256, 0, stream>>>(u_t, dl_t, dbl, Ala, Alb, Sdl, Hloc);
    scan_p2<<<dim3(96, 4), 256, 0, stream>>>(Sdl, Hloc, Ala, Alb, h0);
    scan_p3<<<dim3(6, NC, 4), 256, 0, stream>>>(u_t, dl_t, dbl, h0, Ala, Alb, Da, Db, ya, yb);
    // 7) pack Wo (Sdl dead now); fuse (ya+yb)*silu(z)
    pack_fp16<<<1152, 256, 0, stream>>>(Wo, Wob);
    fuse_y<<<6144, 256, 0, stream>>>(ya, yb, z_t, yf);
    // 8) out_proj (MFMA, f32 out)
    gemm_mfma<float><<<dim3(6, 32, 2), 256, 0, stream>>>(
        yf, Wob, out, DI, DI, DI, DM,
        (long)LQ * DI, 0L, (long)LQ * DM);
}